// Round 8
// baseline (2420.738 us; speedup 1.0000x reference)
//
#include <hip/hip_runtime.h>
#include <hip/hip_bf16.h>
#include <cstdint>
#include <math.h>

typedef __bf16 bf16_t;
typedef bf16_t bf16x8 __attribute__((ext_vector_type(8)));
typedef bf16_t bf16x4 __attribute__((ext_vector_type(4)));
typedef float f32x4 __attribute__((ext_vector_type(4)));

#define B_ 32
#define T_ 2048
#define D_ 256
#define INNER_ 512
#define L_ 3
#define CH16_ 16
#define NCH16_ (T_/CH16_)   // 128 chunks of 16 per batch

typedef const __attribute__((address_space(1))) void* gas_t;
typedef __attribute__((address_space(3))) void* las_t;
__device__ __forceinline__ void gll16(const void* g, void* l) {
  __builtin_amdgcn_global_load_lds((gas_t)g, (las_t)l, 16, 0, 0);
}

struct GemmP {
  const bf16_t* A;
  const bf16_t* Bt;
  const float* bias;
  float* outF;
  bf16_t* outB;
  float* sums;          // act==3: per-16-row-chunk column sums of activated output
  const int* day_ids;   // already offset by group base batch
  long bStrideBt;
  int bStrideBias;
  int K, N, ldout, colOff, act, revA, revC, nValid;
};

// C-tile LDS swizzle: 128 rows x 256 B; xor by (row&7)<<4 breaks the 256-B row
// stride bank aliasing (writes <=4-way, reads 2-way). Low 4 bits untouched.
__device__ __forceinline__ int csw(int row, int colByte) {
  return (row << 8) + (colByte ^ ((row & 7) << 4));
}

// ---------------- GEMM: C = A(MxK) * Bt(NxK)^T, bf16 in, fp32 acc ----------------
// XCD-aware 1-D grid swizzle (bid%8 -> XCD): A-tiles re-served from XCD-local L2
// across N-column blocks. Double-buffered LDS staging via global_load_lds with
// source-side chunk swizzle. MFMA operand order (b_frag, a_frag): n on D's reg
// axis. Epilogue: acc -> LDS C-tile (reusing dead staging buffers) -> contiguous
// 256-B-per-row global_store_dwordx4. act==3 also emits per-16-row chunk sums.
__global__ __launch_bounds__(256, 4)
void gemm_kernel(GemmP p) {
  __shared__ char smem[32768];      // staging: As=smem, Bs=smem+16K; epilogue: C-tile
  bf16_t* As = (bf16_t*)smem;
  bf16_t* Bs = (bf16_t*)(smem + 16384);
  const int tid = threadIdx.x;
  const int wave = tid >> 6, lane = tid & 63;

  // ---- swizzled block decode ----
  const int nb = p.N >> 7;                 // N-blocks (1,2,4,8)
  const int nbs = __builtin_ctz(nb);
  const int c8 = blockIdx.x & 7;           // XCD id under round-robin
  const int k8 = blockIdx.x >> 3;
  const int mGrp = (gridDim.x >> 3) >> nbs;  // M-tiles per XCD
  const int m0 = (c8 * mGrp + (k8 >> nbs)) << 7;
  const int n0 = (k8 & (nb - 1)) << 7;

  const bf16_t* Bt = p.Bt;
  const float* bias = p.bias;
  if (p.day_ids) {
    int day = p.day_ids[m0 >> 11];      // 2048 rows per batch
    Bt += (long)day * p.bStrideBt;
    if (bias) bias += (long)day * p.bStrideBias;
  }
  const int K = p.K;
  const int srow = tid >> 2;                      // 0..63
  const int sc = ((tid & 3) - (tid >> 4)) & 3;    // global chunk this lane stages
  const int sk = sc << 3;                         // element offset of that chunk

  int ar0 = m0 + srow, ar1 = m0 + srow + 64;
  if (p.revA) {
    int t0 = ar0 & (T_-1); ar0 = ar0 - t0 + (T_-1 - t0);
    int t1 = ar1 & (T_-1); ar1 = ar1 - t1 + (T_-1 - t1);
  }
  const bf16_t* aP0 = p.A + (long)ar0 * K + sk;
  const bf16_t* aP1 = p.A + (long)ar1 * K + sk;
  const bf16_t* bP0 = Bt + (long)(n0 + srow) * K + sk;
  const bf16_t* bP1 = bP0 + (long)64 * K;

  char* aL = (char*)As + wave * 1024;   // +4096: rows 64-127; +8192: buffer 1
  char* bL = (char*)Bs + wave * 1024;

  f32x4 acc[4][4] = {};   // [im][in]
  const int mw = ((wave >> 1) << 6), nw = ((wave & 1) << 6);
  const int fr = lane & 15;
  const int foff = (((lane >> 4) + (fr >> 2)) & 3) << 4;  // swizzled chunk byte off

  // prologue: stage tile 0 into buffer 0
  gll16(aP0, aL);
  gll16(aP1, aL + 4096);
  gll16(bP0, bL);
  gll16(bP1, bL + 4096);
  __syncthreads();

  const int nIter = K >> 5;
  for (int it = 0; it < nIter; ++it) {
    const int cur = (it & 1) << 13;     // byte offset of current buffer
    const int nxt = cur ^ 8192;
    if (it + 1 < nIter) {               // prefetch next tile into other buffer
      const int k1 = (it + 1) << 5;
      gll16(aP0 + k1, aL + nxt);
      gll16(aP1 + k1, aL + nxt + 4096);
      gll16(bP0 + k1, bL + nxt);
      gll16(bP1 + k1, bL + nxt + 4096);
    }
    bf16x8 af[4], bfr[4];
#pragma unroll
    for (int i = 0; i < 4; i++)
      af[i] = *(const bf16x8*)((char*)As + cur + (mw + i*16 + fr)*64 + foff);
#pragma unroll
    for (int j = 0; j < 4; j++)
      bfr[j] = *(const bf16x8*)((char*)Bs + cur + (nw + j*16 + fr)*64 + foff);
#pragma unroll
    for (int im = 0; im < 4; im++)
#pragma unroll
      for (int in = 0; in < 4; in++)
        acc[im][in] = __builtin_amdgcn_mfma_f32_16x16x32_bf16(bfr[in], af[im], acc[im][in], 0, 0, 0);
    __syncthreads();   // drains prefetch vmcnt; also frees LDS for the epilogue
  }

  // Lane's C coords: row m = m0+mw+im*16+cn, cols n = n0+nw+in*16+rq+(0..3)
  const int cn = lane & 15, rq = (lane >> 4) << 2;

#pragma unroll
  for (int im = 0; im < 4; im++) {
    int trow = mw + im*16 + cn;          // row within the 128-row tile
    f32x4 cs[4];                         // act==3: this im-group's (16-row) col sums
#pragma unroll
    for (int in = 0; in < 4; in++) {
      int tcolB = (nw + in*16 + rq) << 1;  // byte col within the 256-B tile row
      int colb = n0 + nw + in*16 + rq;
      f32x4 v = acc[im][in];
      if (bias) {
        f32x4 bv = *(const f32x4*)(bias + colb);
        v = v + bv;
      }
      if (p.act == 1) {
#pragma unroll
        for (int r = 0; r < 4; r++) v[r] = v[r] / (1.f + fabsf(v[r]));   // softsign
      } else if (p.act >= 2) {                                           // softplus
#pragma unroll
        for (int r = 0; r < 4; r++) {
          float e = __expf(-fabsf(v[r]));
          v[r] = fmaxf(v[r], 0.f) + __logf(1.f + e);
        }
      }
      cs[in] = v;
      if (p.outB) {
        bf16x4 o;
#pragma unroll
        for (int r = 0; r < 4; r++) o[r] = (bf16_t)v[r];
        *(bf16x4*)(smem + csw(trow, tcolB)) = o;
      }
      if (p.outF) {
        int gr = m0 + trow;
        int orow = gr;
        if (p.revC) { int t = gr & (T_-1); orow = gr - t + (T_-1 - t); }
        long rowOff = (long)orow * p.ldout + p.colOff;
#pragma unroll
        for (int r = 0; r < 4; r++) {
          int col = colb + r;
          if (col < p.nValid) p.outF[rowOff + col] = v[r];
        }
      }
    }
    if (p.act == 3) {
      // reduce this 16-row group's sums across the 16 cn lanes (lane bits 0-3)
#pragma unroll
      for (int in = 0; in < 4; in++) {
#pragma unroll
        for (int b = 1; b < 16; b <<= 1) {
#pragma unroll
          for (int r = 0; r < 4; r++) cs[in][r] += __shfl_xor(cs[in][r], b);
        }
      }
      if (cn == 0) {
        int chunk16 = ((m0 + mw) >> 4) + im;
#pragma unroll
        for (int in = 0; in < 4; in++)
          *(f32x4*)(p.sums + (long)chunk16 * INNER_ + n0 + nw + in*16 + rq) = cs[in];
      }
    }
  }

  if (p.outB) {
    __syncthreads();
    // each iter: 16 rows x (16 lanes x 16 B = full 256-B contiguous row)
    const int rsub = tid >> 4;           // 0..15
    const int cb16 = (tid & 15) << 4;    // byte col, 16-B chunk
#pragma unroll
    for (int itr = 0; itr < 8; ++itr) {
      int trow = (itr << 4) + rsub;
      bf16x8 val = *(const bf16x8*)(smem + csw(trow, cb16));
      int gr = m0 + trow;
      int orow = gr;
      if (p.revC) { int t = gr & (T_-1); orow = gr - t + (T_-1 - t); }
      long off = (long)orow * p.ldout + p.colOff + n0 + (cb16 >> 1);
      *(bf16x8*)(p.outB + off) = val;
    }
  }
}

// ---------------- LayerNorm (one wave per 256-wide row), bf16 in/out -------------
__global__ __launch_bounds__(256)
void ln_kernel(const bf16_t* in, const bf16_t* resid, const float* s, const float* bb,
               bf16_t* outB, int doSilu) {
  int row = (blockIdx.x << 2) + (threadIdx.x >> 6);
  int lane = threadIdx.x & 63;
  long base = (long)row * D_ + (lane << 2);
  bf16x4 iv = *(const bf16x4*)(in + base);
  float v[4];
#pragma unroll
  for (int k = 0; k < 4; k++) v[k] = (float)iv[k];
  if (resid) {
    bf16x4 rv = *(const bf16x4*)(resid + base);
#pragma unroll
    for (int k = 0; k < 4; k++) v[k] += (float)rv[k];
  }
  float s1 = v[0] + v[1] + v[2] + v[3];
  float s2 = v[0]*v[0] + v[1]*v[1] + v[2]*v[2] + v[3]*v[3];
#pragma unroll
  for (int off = 1; off < 64; off <<= 1) {
    s1 += __shfl_xor(s1, off);
    s2 += __shfl_xor(s2, off);
  }
  float mean = s1 * (1.f / D_);
  float var = s2 * (1.f / D_) - mean * mean;
  float inv = rsqrtf(var + 1e-5f);
  f32x4 sv = *(const f32x4*)(s + (lane << 2));
  f32x4 bv = *(const f32x4*)(bb + (lane << 2));
  bf16x4 ov;
#pragma unroll
  for (int k = 0; k < 4; k++) {
    float val = (v[k] - mean) * inv * sv[k] + bv[k];
    if (doSilu) val = val / (1.f + __expf(-val));
    ov[k] = (bf16_t)val;
  }
  *(bf16x4*)(outB + base) = ov;
}

// ---------------- depthwise conv (taps t-2..t+1) + bias + silu, x8 vectorized ----
__global__ __launch_bounds__(256)
void conv_kernel(const bf16_t* xz, const float* K4, const float* cb, bf16_t* xc) {
  long idx = (long)blockIdx.x * 256 + threadIdx.x;
  int ch0 = ((int)(idx & 63)) << 3;
  long bt = idx >> 6;
  int t = (int)(bt & (T_-1));
  const bf16_t* base = xz + bt * (2*INNER_) + ch0;
  bf16x8 r0, r1, r2, r3;
  r2 = *(const bf16x8*)(base);
#pragma unroll
  for (int k = 0; k < 8; k++) { r0[k] = (bf16_t)0.f; r1[k] = (bf16_t)0.f; r3[k] = (bf16_t)0.f; }
  if (t >= 2) r0 = *(const bf16x8*)(base - 2*(2*INNER_));
  if (t >= 1) r1 = *(const bf16x8*)(base - (2*INNER_));
  if (t < T_-1) r3 = *(const bf16x8*)(base + (2*INNER_));
  bf16x8 o8;
#pragma unroll
  for (int k = 0; k < 8; k++) {
    f32x4 kk = *(const f32x4*)(K4 + ((ch0 + k) << 2));
    float a = cb[ch0 + k] + (float)r0[k]*kk[0] + (float)r1[k]*kk[1]
            + (float)r2[k]*kk[2] + (float)r3[k]*kk[3];
    o8[k] = (bf16_t)(a / (1.f + __expf(-a)));
  }
  *(bf16x8*)(xc + bt * INNER_ + ch0) = o8;
}

// ---------------- exclusive scan over the 128 chunk16 sums per (batch, channel) --
__global__ __launch_bounds__(256)
void scan_kernel(float* sums) {
  int id = blockIdx.x * 256 + threadIdx.x;   // Bg*512 threads
  int b = id >> 9, ch = id & 511;
  float* sp = sums + (long)b * NCH16_ * INNER_ + ch;
  float run = 0.f;
#pragma unroll 4
  for (int c = 0; c < NCH16_; c++) {
    float v = sp[(long)c << 9];
    sp[(long)c << 9] = run;
    run += v;
  }
}

// y = xc * w * silu(z) in place over xc; one wave per 16-timestep chunk ----------
__global__ __launch_bounds__(256)
void y_kernel(const bf16_t* dt, const bf16_t* xz, bf16_t* xc, const float* sums) {
  int bc = blockIdx.x * 4 + (threadIdx.x >> 6);   // global chunk16 id
  int ch0 = (threadIdx.x & 63) << 3;
  const float* sp = sums + (long)bc * INNER_ + ch0;  // exclusive prefix (post-scan)
  float acc[8];
  f32x4 a0 = *(const f32x4*)sp, a1 = *(const f32x4*)(sp + 4);
#pragma unroll
  for (int k = 0; k < 4; k++) { acc[k] = a0[k]; acc[k+4] = a1[k]; }
  long bt0 = (long)bc * CH16_;
#pragma unroll
  for (int i = 0; i < CH16_; i++) {
    long bt = bt0 + i;
    bf16x8 d8 = *(const bf16x8*)(dt + bt * INNER_ + ch0);
    bf16x8 z8 = *(const bf16x8*)(xz + bt * (2*INNER_) + INNER_ + ch0);
    bf16x8 x8 = *(const bf16x8*)(xc + bt * INNER_ + ch0);
    bf16x8 o8;
#pragma unroll
    for (int k = 0; k < 8; k++) {
      acc[k] += (float)d8[k];
      float w = __expf(-0.1f * acc[k]);
      float zz = (float)z8[k];
      float sz = zz / (1.f + __expf(-zz));
      o8[k] = (bf16_t)((float)x8[k] * w * sz);
    }
    *(bf16x8*)(xc + bt * INNER_ + ch0) = o8;
  }
}

// ---------------- log_softmax over 41 (one wave per row) -------------------------
__global__ __launch_bounds__(256)
void lsm_kernel(const float* logits, float* out) {
  int row = (blockIdx.x << 2) + (threadIdx.x >> 6);
  int lane = threadIdx.x & 63;
  float v = (lane < 41) ? logits[(long)row * 41 + lane] : -3.4e38f;
  float m = v;
#pragma unroll
  for (int off = 1; off < 64; off <<= 1) m = fmaxf(m, __shfl_xor(m, off));
  float e = (lane < 41) ? __expf(v - m) : 0.f;
  float ssum = e;
#pragma unroll
  for (int off = 1; off < 64; off <<= 1) ssum += __shfl_xor(ssum, off);
  float ls = __logf(ssum);
  if (lane < 41) out[(long)row * 41 + lane] = v - m - ls;
}

// ---------------- fp32 (R,C) -> bf16 (C,R) transpose, batched via z --------------
__global__ void tconv_kernel(const float* in, bf16_t* out, int R, int C) {
  __shared__ float tile[32][33];
  const float* ip = in + (long)blockIdx.z * R * C;
  bf16_t* op = out + (long)blockIdx.z * R * C;
  int c0 = blockIdx.x << 5, r0 = blockIdx.y << 5;
  int tx = threadIdx.x, ty = threadIdx.y;
  for (int i = ty; i < 32; i += 8) {
    int r = r0 + i, c = c0 + tx;
    tile[i][tx] = (r < R && c < C) ? ip[(long)r * C + c] : 0.f;
  }
  __syncthreads();
  for (int i = ty; i < 32; i += 8) {
    int c = c0 + i, r = r0 + tx;
    if (c < C && r < R) op[(long)c * R + r] = (bf16_t)tile[tx][i];
  }
}

__global__ void cvt_kernel(const float* in, bf16_t* out, long n) {
  long i = ((long)blockIdx.x * blockDim.x + threadIdx.x) << 3;
  if (i >= n) return;
  f32x4 a = *(const f32x4*)(in + i);
  f32x4 b = *(const f32x4*)(in + i + 4);
  bf16x8 o;
#pragma unroll
  for (int k = 0; k < 4; k++) { o[k] = (bf16_t)a[k]; o[k+4] = (bf16_t)b[k]; }
  *(bf16x8*)(out + i) = o;
}

__global__ void zfill_kernel(bf16_t* p, int n) {
  int i = blockIdx.x * 256 + threadIdx.x;
  if (i < n) p[i] = (bf16_t)0.f;
}

extern "C" void kernel_launch(void* const* d_in, const int* in_sizes, int n_in,
                              void* d_out, int out_size, void* d_ws, size_t ws_size,
                              hipStream_t stream) {
  (void)in_sizes; (void)n_in; (void)out_size;
  const float* x         = (const float*)d_in[0];
  const int*   day_ids   = (const int*)d_in[1];
  const float* adapter_W = (const float*)d_in[2];
  const float* adapter_b = (const float*)d_in[3];
  const float* cW1       = (const float*)d_in[4];
  const float* cb1       = (const float*)d_in[5];
  const float* cln1_s    = (const float*)d_in[6];
  const float* cln1_b    = (const float*)d_in[7];
  const float* cW2       = (const float*)d_in[8];
  const float* cb2       = (const float*)d_in[9];
  const float* cln2_s    = (const float*)d_in[10];
  const float* cln2_b    = (const float*)d_in[11];
  const float* m_in      = (const float*)d_in[12];
  const float* m_convK   = (const float*)d_in[13];
  const float* m_convB   = (const float*)d_in[14];
  const float* m_dtW     = (const float*)d_in[15];
  const float* m_dtB     = (const float*)d_in[16];
  const float* m_out     = (const float*)d_in[17];
  const float* proj_W    = (const float*)d_in[18];
  const float* proj_b    = (const float*)d_in[19];
  const float* norm_s    = (const float*)d_in[20];
  const float* norm_b    = (const float*)d_in[21];
  const float* outW      = (const float*)d_in[22];
  const float* outb      = (const float*)d_in[23];
  float* out = (float*)d_out;

  char* ws = (char*)d_ws;
  size_t off = 0;
  auto alloc = [&](size_t bytes) -> char* {
    char* p = ws + off;
    off += (bytes + 255) & ~(size_t)255;
    return p;
  };
  // ---- fixed: transposed bf16 weights (~33 MB) ----
  bf16_t* adapterT = (bf16_t*)alloc((size_t)45*512*512*2);
  bf16_t* cW1T     = (bf16_t*)alloc((size_t)256*512*2);
  bf16_t* cW2T     = (bf16_t*)alloc((size_t)256*256*2);
  bf16_t* m_inT    = (bf16_t*)alloc((size_t)6*1024*256*2);
  bf16_t* m_dtWT   = (bf16_t*)alloc((size_t)6*512*512*2);
  bf16_t* m_outT   = (bf16_t*)alloc((size_t)6*256*512*2);
  bf16_t* projT    = (bf16_t*)alloc((size_t)3*256*512*2);
  bf16_t* outWT    = (bf16_t*)alloc((size_t)128*256*2);

  // ---- adaptive group size: largest Bg whose regions fit ws_size ----
  int Bg = 0;
  {
    const int cands[6] = {32, 16, 8, 4, 2, 1};
    for (int ci = 0; ci < 6; ci++) {
      int c = cands[ci];
      size_t Mg = (size_t)c * T_;
      size_t need = Mg*2048 + 3*(Mg*1024) + Mg*512 + (size_t)c*NCH16_*INNER_*4
                    + 8*256;  // alignment slack
      if (off + need <= ws_size) { Bg = c; break; }
    }
  }
  if (Bg == 0) return;  // workspace too small to run at all
  const size_t Mg = (size_t)Bg * T_;
  char*  xzR  = alloc(Mg * 2048);          // xz (Mg x 1024 bf16); also x_bf, logits
  char*  xcR  = alloc(Mg * 1024);          // xc / y (Mg x 512 bf16); also h0
  char*  dtR  = alloc(Mg * 1024);          // dt (Mg x 512 bf16); also tmp pre-LN bf16
  char*  swR  = alloc(Mg * 1024);          // swcat (Mg x 512 bf16); also h1
  bf16_t* hG  = (bf16_t*)alloc(Mg * 512);  // h (Mg x 256 bf16)
  float* sums = (float*)alloc((size_t)Bg * NCH16_ * INNER_ * 4);

  // ---- weight conversion/transpose (once) ----
  zfill_kernel<<<128, 256, 0, stream>>>(outWT, 128*256);
  dim3 tb(32, 8);
  tconv_kernel<<<dim3(16,16,45), tb, 0, stream>>>(adapter_W, adapterT, 512, 512);
  tconv_kernel<<<dim3(8,16,1),  tb, 0, stream>>>(cW1,  cW1T,  512, 256);
  tconv_kernel<<<dim3(8,8,1),   tb, 0, stream>>>(cW2,  cW2T,  256, 256);
  tconv_kernel<<<dim3(32,8,6),  tb, 0, stream>>>(m_in, m_inT, 256, 1024);
  tconv_kernel<<<dim3(16,16,6), tb, 0, stream>>>(m_dtW, m_dtWT, 512, 512);
  tconv_kernel<<<dim3(8,16,6),  tb, 0, stream>>>(m_out, m_outT, 512, 256);
  tconv_kernel<<<dim3(8,16,3),  tb, 0, stream>>>(proj_W, projT, 512, 256);
  tconv_kernel<<<dim3(2,8,1),   tb, 0, stream>>>(outW, outWT, 256, 41);

  auto gemm = [&](const bf16_t* A, const bf16_t* Bt, const float* bias,
                  float* outF, bf16_t* outB, int K, int N, int ldout, int colOff,
                  int act, int revA, int revC, const int* days, long bsBt, int bsBias,
                  int nValid, float* sumsP) {
    GemmP p;
    p.A = A; p.Bt = Bt; p.bias = bias; p.outF = outF; p.outB = outB; p.sums = sumsP;
    p.day_ids = days; p.bStrideBt = bsBt; p.bStrideBias = bsBias;
    p.K = K; p.N = N; p.ldout = ldout; p.colOff = colOff;
    p.act = act; p.revA = revA; p.revC = revC; p.nValid = nValid;
    gemm_kernel<<<dim3((unsigned)((Mg/128) * (N/128))), 256, 0, stream>>>(p);
  };

  for (int b0 = 0; b0 < B_; b0 += Bg) {
    const float* xg = x + (size_t)b0 * T_ * 512;

    // ---- x -> bf16 ----
    bf16_t* x_bf = (bf16_t*)xzR;
    cvt_kernel<<<(unsigned)(Mg/4), 256, 0, stream>>>(xg, x_bf, (long)Mg*512);

    // ---- adapter: h0 = softsign(x @ W[day] + b[day]) ----
    bf16_t* h0 = (bf16_t*)xcR;
    gemm(x_bf, adapterT, adapter_b, nullptr, h0, 512, 512, 512, 0, /*act*/1, 0, 0,
         day_ids + b0, (long)512*512, 512, 512, nullptr);

    // ---- h1 = silu(LN(h0 @ cW1 + cb1)) ----
    bf16_t* tmpB = (bf16_t*)dtR;
    gemm(h0, cW1T, cb1, nullptr, tmpB, 512, 256, 256, 0, 0, 0, 0, nullptr, 0, 0, 256, nullptr);
    bf16_t* h1 = (bf16_t*)swR;
    ln_kernel<<<(unsigned)(Mg/4), 256, 0, stream>>>(tmpB, nullptr, cln1_s, cln1_b, h1, 1);

    // ---- h = silu(LN(h1 @ cW2 + cb2)) ----
    gemm(h1, cW2T, cb2, nullptr, tmpB, 256, 256, 256, 0, 0, 0, 0, nullptr, 0, 0, 256, nullptr);
    ln_kernel<<<(unsigned)(Mg/4), 256, 0, stream>>>(tmpB, nullptr, cln2_s, cln2_b, hG, 1);

    bf16_t* xz    = (bf16_t*)xzR;
    bf16_t* xc    = (bf16_t*)xcR;
    bf16_t* dt    = (bf16_t*)dtR;
    bf16_t* swcat = (bf16_t*)swR;

    for (int l = 0; l < L_; l++) {
      for (int dir = 0; dir < 2; dir++) {
        int ld = l*2 + dir;
        // xz = h @ Win (reversed read of h for dir=1)
        gemm(hG, m_inT + (size_t)ld*1024*256, nullptr, nullptr, xz,
             256, 1024, 1024, 0, 0, /*revA*/dir, 0, nullptr, 0, 0, 1024, nullptr);
        // xc = silu(dwconv(xi) + convB)
        conv_kernel<<<(unsigned)(Mg/4), 256, 0, stream>>>(
            xz, m_convK + (size_t)ld*512*4, m_convB + (size_t)ld*512, xc);
        // dt = softplus(xc @ dtW + dtB); epilogue emits per-16-row chunk col sums
        gemm(xc, m_dtWT + (size_t)ld*512*512, m_dtB + (size_t)ld*512, nullptr, dt,
             512, 512, 512, 0, /*act*/3, 0, 0, nullptr, 0, 0, 512, sums);
        // exclusive prefix over chunk sums, then y = xc * w * silu(z) in place
        scan_kernel<<<(unsigned)(Bg*2), 256, 0, stream>>>(sums);
        y_kernel<<<(unsigned)(Mg/64), 256, 0, stream>>>(dt, xz, xc, sums);
        // swcat[:, dir*256:...] = y @ Wout (store reversed for dir=1)
        gemm(xc, m_outT + (size_t)ld*256*512, nullptr, nullptr, swcat,
             512, 256, 512, dir*256, 0, 0, /*revC*/dir, nullptr, 0, 0, 256, nullptr);
      }
      // combined = swcat @ proj_W + proj_b; h = LN(h + combined)
      bf16_t* tmpB2 = (bf16_t*)dtR;
      gemm(swcat, projT + (size_t)l*256*512, proj_b + (size_t)l*256, nullptr, tmpB2,
           512, 256, 256, 0, 0, 0, 0, nullptr, 0, 0, 256, nullptr);
      ln_kernel<<<(unsigned)(Mg/4), 256, 0, stream>>>(tmpB2, hG, norm_s + (size_t)l*256,
                                                      norm_b + (size_t)l*256, hG, 0);
    }

    // ---- logits + log_softmax ----
    float* logits = (float*)xzR;
    gemm(hG, outWT, outb, logits, nullptr, 256, 128, 41, 0, 0, 0, 0,
         nullptr, 0, 0, 41, nullptr);
    lsm_kernel<<<(unsigned)(Mg/4), 256, 0, stream>>>(logits, out + (size_t)b0 * T_ * 41);
  }
}